// Round 1
// baseline (2095.340 us; speedup 1.0000x reference)
//
#include <hip/hip_runtime.h>

#define N 128
#define NITER 60
#define RPS 129   // row-partial stride: ODD -> publish banks (tc+8g+r)%32 = uniform 2-way (free)
#define CPS 130   // col-partial stride: even (8B-aligned v2 stores), 4-way publish, 2-way reduce

typedef float v2f __attribute__((ext_vector_type(2)));
typedef float v4f __attribute__((ext_vector_type(4)));

// Two batch rows per block, staggered: each barrier window does
//   [update+publish row Q]  overlapped with  [reduce+y-store row P]
// so every window has a dense VALU block (~420 cyc) under which the 32
// reduce LDS loads (issued early into rtmp/ctmp, summed after the update)
// and the publish stores hide. 1 barrier per row-iteration instead of 2.
// Arithmetic is expression-identical to the 1-row kernel -> bitwise-same output.
template<int Q, int P>
__device__ __forceinline__ void window_step(
    v2f (&z2)[2][8][4], const v2f (&w2)[2][8][4],
    float (&RP)[2][16 * RPS], float (&CP)[2][16 * CPS],
    float (&YV)[2][N],
    int tid, int tr, int tc, int i0, int j0,
    float xiP, bool storeCond, bool rawStore)
{
    const float step = 1.0f / 256.0f;   // 1/(2N), exact power of two

    // y-broadcast for the update of row Q (written last window, across barrier)
    v2f drs[8], ec2[4], pr2[8], pc2[4];
    #pragma unroll
    for (int r = 0; r < 8; ++r) drs[r] = (v2f)YV[Q][i0 + r];   // 16-lane broadcast reads
    const v2f* yv2 = (const v2f*)YV[Q];
    #pragma unroll
    for (int cp = 0; cp < 4; ++cp) ec2[cp] = yv2[tc * 4 + cp];

    // Issue the other row's reduce loads NOW (no uses yet -> no stall);
    // their latency dies under the update loop below. At it==0 these read
    // garbage that is discarded (storeCond=false).
    float rtmp[16], ctmp[16];
    const int ridx = tid & (N - 1);
    if (tid < N) {
        #pragma unroll
        for (int k = 0; k < 16; ++k) rtmp[k] = RP[P][k * RPS + ridx];  // banks (k+tid)%32: 2-way
        #pragma unroll
        for (int k = 0; k < 16; ++k) ctmp[k] = CP[P][k * CPS + ridx];  // banks (2k+tid)%32: 2-way
    }

    #pragma unroll
    for (int r = 0; r < 8; ++r) pr2[r] = (v2f)0.0f;
    #pragma unroll
    for (int cp = 0; cp < 4; ++cp) pc2[cp] = (v2f)0.0f;

    // packed dual update + partial-sum accumulation (identical math/order to 1-row kernel)
    #pragma unroll
    for (int r = 0; r < 8; ++r) {
        #pragma unroll
        for (int cp = 0; cp < 4; ++cp) {
            v2f t  = (z2[Q][r][cp] + drs[r]) - ec2[cp];   // 2x v_pk_add_f32
            v2f wv = w2[Q][r][cp];
            v2f zn;
            zn.x = __builtin_amdgcn_fmed3f(t.x, -wv.x, wv.x);
            zn.y = __builtin_amdgcn_fmed3f(t.y, -wv.y, wv.y);
            z2[Q][r][cp] = zn;
            pr2[r]  += zn;
            pc2[cp] += zn;
        }
    }

    // publish row Q partials. RPS=129 odd -> scalar b32 stores at uniform 2-way banks.
    #pragma unroll
    for (int r = 0; r < 8; ++r)
        RP[Q][tc * RPS + i0 + r] = pr2[r].x + pr2[r].y;
    v2f* cd = (v2f*)&CP[Q][tr * CPS + j0];
    #pragma unroll
    for (int cp = 0; cp < 4; ++cp) cd[cp] = pc2[cp];

    // finish row P's reduce: single-chain sums in the ORIGINAL k order (bitwise identical)
    if (storeCond) {
        float rs = 0.0f, cs = 0.0f;
        #pragma unroll
        for (int k = 0; k < 16; ++k) rs += rtmp[k];
        #pragma unroll
        for (int k = 0; k < 16; ++k) cs += ctmp[k];
        float y = xiP - rs + cs;
        YV[P][tid] = rawStore ? y : step * y;
    }
}

__global__ __launch_bounds__(256, 2)
void gfusedmax_kernel(const float* __restrict__ x,
                      const float* __restrict__ A,
                      float* __restrict__ out)
{
    const int b0  = blockIdx.x * 2;
    const int tid = threadIdx.x;
    const int tr  = tid >> 4;   // 0..15
    const int tc  = tid & 15;   // 0..15
    const int i0  = tr * 8;
    const int j0  = tc * 8;

    __shared__ float RP[2][16 * RPS];
    __shared__ __align__(16) float CP[2][16 * CPS];
    __shared__ __align__(16) float YV[2][N];
    __shared__ float sorted[2][N];
    __shared__ float red[2][4];

    const float step = 1.0f / 256.0f;

    // ---- load w = lam*A tiles for both rows as pairs, init z=0 ----
    v2f w2[2][8][4];
    v2f z2[2][8][4];
    #pragma unroll
    for (int q = 0; q < 2; ++q) {
        const float* Ab = A + (size_t)(b0 + q) * N * N;
        #pragma unroll
        for (int r = 0; r < 8; ++r) {
            const v4f* src = (const v4f*)(Ab + (size_t)(i0 + r) * N + j0);
            v4f p0 = src[0];
            v4f p1 = src[1];
            w2[q][r][0] = p0.lo; w2[q][r][1] = p0.hi;
            w2[q][r][2] = p1.lo; w2[q][r][3] = p1.hi;
            #pragma unroll
            for (int cp = 0; cp < 4; ++cp) z2[q][r][cp] = (v2f)0.0f;
        }
    }

    float xi0 = 0.0f, xi1 = 0.0f;
    if (tid < N) {
        xi0 = x[(size_t)b0 * N + tid];
        xi1 = x[(size_t)(b0 + 1) * N + tid];
        // iteration-0 y is just x (partials are zero): seed step*x directly
        YV[0][tid] = step * xi0;
        YV[1][tid] = step * xi1;
    }
    __syncthreads();

    for (int it = 0; it < NITER; ++it) {
        // window A: update row0 (y from prev window B / prologue), publish RP/CP[0];
        //           reduce row1 from RP/CP[1] (skip at it==0: prologue already seeded y1)
        window_step<0, 1>(z2, w2, RP, CP, YV, tid, tr, tc, i0, j0,
                          xi1, (it != 0) && (tid < N), false);
        __syncthreads();
        // window B: update row1 (y written just above), publish RP/CP[1];
        //           reduce row0 -> y for row0's next update (raw y on the final reduce)
        window_step<1, 0>(z2, w2, RP, CP, YV, tid, tr, tc, i0, j0,
                          xi0, (tid < N), it == NITER - 1);
        __syncthreads();
    }

    // epilogue: final (raw) reduce for row1 from the last window-B publish
    if (tid < N) {
        float rs = 0.0f, cs = 0.0f;
        #pragma unroll
        for (int k = 0; k < 16; ++k) rs += RP[1][k * RPS + tid];
        #pragma unroll
        for (int k = 0; k < 16; ++k) cs += CP[1][k * CPS + tid];
        YV[1][tid] = xi1 - rs + cs;
    }
    __syncthreads();

    // ---- sparsemax: waves 0-1 handle row0, waves 2-3 handle row1 ----
    const int row = tid >> 7;        // 0 or 1
    const int t1  = tid & 127;
    const float* yrow = YV[row];
    float v = yrow[t1];
    int rk = 0;
    for (int k = 0; k < N; ++k) {
        float u = yrow[k];
        rk += (u > v) || (u == v && k < t1);
    }
    sorted[row][rk] = v;   // rank is a permutation (ties broken by index)
    __syncthreads();

    float s = sorted[row][t1];
    float csum = 0.0f;
    for (int m = 0; m < N; ++m) {            // uniform index -> LDS broadcast
        float t = sorted[row][m];
        if (m <= t1) csum += t;              // inclusive prefix at sorted pos
    }
    bool mask = (1.0f + (float)(t1 + 1) * s > csum);
    float aRed = mask ? s : 0.0f;
    float bRed = mask ? 1.0f : 0.0f;
    #pragma unroll
    for (int off = 32; off >= 1; off >>= 1) {
        aRed += __shfl_down(aRed, off, 64);
        bRed += __shfl_down(bRed, off, 64);
    }
    const int wid2 = (tid >> 6) & 1;         // wave index within the row's 2 waves
    if ((tid & 63) == 0) { red[row][wid2 * 2] = aRed; red[row][wid2 * 2 + 1] = bRed; }
    __syncthreads();
    const float tau = (red[row][0] + red[row][2] - 1.0f)
                    / (red[row][1] + red[row][3]);
    out[(size_t)(b0 + row) * N + t1] = fmaxf(v - tau, 0.0f);
}

extern "C" void kernel_launch(void* const* d_in, const int* in_sizes, int n_in,
                              void* d_out, int out_size, void* d_ws, size_t ws_size,
                              hipStream_t stream) {
    const float* x = (const float*)d_in[0];
    const float* A = (const float*)d_in[1];
    float* out = (float*)d_out;
    const int B = in_sizes[0] / N;   // 4096 rows
    gfusedmax_kernel<<<B / 2, 256, 0, stream>>>(x, A, out);
}

// Round 2
// 1198.557 us; speedup vs baseline: 1.7482x; 1.7482x over previous
//
#include <hip/hip_runtime.h>

#define N 128
#define NITER 60
#define RPS 129   // row-partial stride: ODD -> publish banks (tc+8g+r)%32 = uniform 2-way (free)
#define CPS 130   // col-partial stride: even (8B-aligned v2 stores), 4-way publish, 2-way reduce

typedef float v2f __attribute__((ext_vector_type(2)));
typedef float v4f __attribute__((ext_vector_type(4)));

// Two batch rows per block, staggered: each barrier window does
//   [update+publish row Q]  overlapped with  [reduce+y-store row P]
// so every window has a dense VALU block (~540 cyc issue) under which the 32
// reduce LDS loads (issued early into rtmp/ctmp, summed after the update)
// and the publish stores hide. 1 barrier per row-iteration instead of 2.
//
// R1 lesson: persistent state is 2x(w2+z2) = 256 VGPR-floats/thread + ~100
// window temps. __launch_bounds__(256,2) capped the wave at 256 VGPRs ->
// ~9KB/thread scratch spill -> 4.8 GB HBM scratch traffic (FETCH_SIZE counter)
// and 2.7x regression. (256,1) lifts the cap to 512: the whole working set
// stays in registers; we trade occupancy (1 wave/SIMD) for spill-free ILP,
// which is the design's actual latency-hiding mechanism.
template<int Q, int P>
__device__ __forceinline__ void window_step(
    v2f (&z2)[2][8][4], const v2f (&w2)[2][8][4],
    float (&RP)[2][16 * RPS], float (&CP)[2][16 * CPS],
    float (&YV)[2][N],
    int tid, int tr, int tc, int i0, int j0,
    float xiP, bool storeCond, bool rawStore)
{
    const float step = 1.0f / 256.0f;   // 1/(2N), exact power of two

    // y-broadcast for the update of row Q (written last window, across barrier)
    v2f drs[8], ec2[4], pr2[8], pc2[4];
    #pragma unroll
    for (int r = 0; r < 8; ++r) drs[r] = (v2f)YV[Q][i0 + r];   // 16-lane broadcast reads
    const v2f* yv2 = (const v2f*)YV[Q];
    #pragma unroll
    for (int cp = 0; cp < 4; ++cp) ec2[cp] = yv2[tc * 4 + cp];

    // Issue the other row's reduce loads NOW (no uses yet -> no stall);
    // their latency dies under the update loop below. At it==0 these read
    // garbage that is discarded (storeCond=false).
    float rtmp[16], ctmp[16];
    const int ridx = tid & (N - 1);
    if (tid < N) {
        #pragma unroll
        for (int k = 0; k < 16; ++k) rtmp[k] = RP[P][k * RPS + ridx];  // banks (k+tid)%32: 2-way
        #pragma unroll
        for (int k = 0; k < 16; ++k) ctmp[k] = CP[P][k * CPS + ridx];  // banks (2k+tid)%32: 2-way
    }

    #pragma unroll
    for (int r = 0; r < 8; ++r) pr2[r] = (v2f)0.0f;
    #pragma unroll
    for (int cp = 0; cp < 4; ++cp) pc2[cp] = (v2f)0.0f;

    // packed dual update + partial-sum accumulation (identical math/order to 1-row kernel)
    #pragma unroll
    for (int r = 0; r < 8; ++r) {
        #pragma unroll
        for (int cp = 0; cp < 4; ++cp) {
            v2f t  = (z2[Q][r][cp] + drs[r]) - ec2[cp];   // 2x v_pk_add_f32
            v2f wv = w2[Q][r][cp];
            v2f zn;
            zn.x = __builtin_amdgcn_fmed3f(t.x, -wv.x, wv.x);
            zn.y = __builtin_amdgcn_fmed3f(t.y, -wv.y, wv.y);
            z2[Q][r][cp] = zn;
            pr2[r]  += zn;
            pc2[cp] += zn;
        }
    }

    // publish row Q partials. RPS=129 odd -> scalar b32 stores at uniform 2-way banks.
    #pragma unroll
    for (int r = 0; r < 8; ++r)
        RP[Q][tc * RPS + i0 + r] = pr2[r].x + pr2[r].y;
    v2f* cd = (v2f*)&CP[Q][tr * CPS + j0];
    #pragma unroll
    for (int cp = 0; cp < 4; ++cp) cd[cp] = pc2[cp];

    // finish row P's reduce: single-chain sums in the ORIGINAL k order (bitwise identical)
    if (storeCond) {
        float rs = 0.0f, cs = 0.0f;
        #pragma unroll
        for (int k = 0; k < 16; ++k) rs += rtmp[k];
        #pragma unroll
        for (int k = 0; k < 16; ++k) cs += ctmp[k];
        float y = xiP - rs + cs;
        YV[P][tid] = rawStore ? y : step * y;
    }
}

__global__ __launch_bounds__(256, 1)
void gfusedmax_kernel(const float* __restrict__ x,
                      const float* __restrict__ A,
                      float* __restrict__ out)
{
    const int b0  = blockIdx.x * 2;
    const int tid = threadIdx.x;
    const int tr  = tid >> 4;   // 0..15
    const int tc  = tid & 15;   // 0..15
    const int i0  = tr * 8;
    const int j0  = tc * 8;

    __shared__ float RP[2][16 * RPS];
    __shared__ __align__(16) float CP[2][16 * CPS];
    __shared__ __align__(16) float YV[2][N];
    __shared__ float sorted[2][N];
    __shared__ float red[2][4];

    const float step = 1.0f / 256.0f;

    // ---- load w = lam*A tiles for both rows as pairs, init z=0 ----
    v2f w2[2][8][4];
    v2f z2[2][8][4];
    #pragma unroll
    for (int q = 0; q < 2; ++q) {
        const float* Ab = A + (size_t)(b0 + q) * N * N;
        #pragma unroll
        for (int r = 0; r < 8; ++r) {
            const v4f* src = (const v4f*)(Ab + (size_t)(i0 + r) * N + j0);
            v4f p0 = src[0];
            v4f p1 = src[1];
            w2[q][r][0] = p0.lo; w2[q][r][1] = p0.hi;
            w2[q][r][2] = p1.lo; w2[q][r][3] = p1.hi;
            #pragma unroll
            for (int cp = 0; cp < 4; ++cp) z2[q][r][cp] = (v2f)0.0f;
        }
    }

    float xi0 = 0.0f, xi1 = 0.0f;
    if (tid < N) {
        xi0 = x[(size_t)b0 * N + tid];
        xi1 = x[(size_t)(b0 + 1) * N + tid];
        // iteration-0 y is just x (partials are zero): seed step*x directly
        YV[0][tid] = step * xi0;
        YV[1][tid] = step * xi1;
    }
    __syncthreads();

    for (int it = 0; it < NITER; ++it) {
        // window A: update row0 (y from prev window B / prologue), publish RP/CP[0];
        //           reduce row1 from RP/CP[1] (skip at it==0: prologue already seeded y1)
        window_step<0, 1>(z2, w2, RP, CP, YV, tid, tr, tc, i0, j0,
                          xi1, (it != 0) && (tid < N), false);
        __syncthreads();
        // window B: update row1 (y written just above), publish RP/CP[1];
        //           reduce row0 -> y for row0's next update (raw y on the final reduce)
        window_step<1, 0>(z2, w2, RP, CP, YV, tid, tr, tc, i0, j0,
                          xi0, (tid < N), it == NITER - 1);
        __syncthreads();
    }

    // epilogue: final (raw) reduce for row1 from the last window-B publish
    if (tid < N) {
        float rs = 0.0f, cs = 0.0f;
        #pragma unroll
        for (int k = 0; k < 16; ++k) rs += RP[1][k * RPS + tid];
        #pragma unroll
        for (int k = 0; k < 16; ++k) cs += CP[1][k * CPS + tid];
        YV[1][tid] = xi1 - rs + cs;
    }
    __syncthreads();

    // ---- sparsemax: waves 0-1 handle row0, waves 2-3 handle row1 ----
    const int row = tid >> 7;        // 0 or 1
    const int t1  = tid & 127;
    const float* yrow = YV[row];
    float v = yrow[t1];
    int rk = 0;
    for (int k = 0; k < N; ++k) {
        float u = yrow[k];
        rk += (u > v) || (u == v && k < t1);
    }
    sorted[row][rk] = v;   // rank is a permutation (ties broken by index)
    __syncthreads();

    float s = sorted[row][t1];
    float csum = 0.0f;
    for (int m = 0; m < N; ++m) {            // uniform index -> LDS broadcast
        float t = sorted[row][m];
        if (m <= t1) csum += t;              // inclusive prefix at sorted pos
    }
    bool mask = (1.0f + (float)(t1 + 1) * s > csum);
    float aRed = mask ? s : 0.0f;
    float bRed = mask ? 1.0f : 0.0f;
    #pragma unroll
    for (int off = 32; off >= 1; off >>= 1) {
        aRed += __shfl_down(aRed, off, 64);
        bRed += __shfl_down(bRed, off, 64);
    }
    const int wid2 = (tid >> 6) & 1;         // wave index within the row's 2 waves
    if ((tid & 63) == 0) { red[row][wid2 * 2] = aRed; red[row][wid2 * 2 + 1] = bRed; }
    __syncthreads();
    const float tau = (red[row][0] + red[row][2] - 1.0f)
                    / (red[row][1] + red[row][3]);
    out[(size_t)(b0 + row) * N + t1] = fmaxf(v - tau, 0.0f);
}

extern "C" void kernel_launch(void* const* d_in, const int* in_sizes, int n_in,
                              void* d_out, int out_size, void* d_ws, size_t ws_size,
                              hipStream_t stream) {
    const float* x = (const float*)d_in[0];
    const float* A = (const float*)d_in[1];
    float* out = (float*)d_out;
    const int B = in_sizes[0] / N;   // 4096 rows
    gfusedmax_kernel<<<B / 2, 256, 0, stream>>>(x, A, out);
}

// Round 4
// 826.729 us; speedup vs baseline: 2.5345x; 1.4498x over previous
//
#include <hip/hip_runtime.h>

#define N 128
#define NITER 60
#define PST 132      // partial-row stride (floats): multiple of 4 -> 16B-aligned rows for b128
#define COLOFF 2128  // colpart base offset: 16*PST=2112 rounded up so COLOFF%32==16 (bank shift)

typedef float v2f __attribute__((ext_vector_type(2)));
typedef float v4f __attribute__((ext_vector_type(4)));

// Round-0 structure (1 batch row / block, 2 barriers/iter, 2 blocks/CU
// cross-block TLP — R1/R2 showed 2-row staggering halves resident blocks and
// loses). This version cuts LDS-pipe pressure, the co-bottleneck:
//  - publishes as b128 (contiguous [tc][i0..] rows): starts (4tc+8tr)%32 give
//    8 lanes per 4-bank window = even = conflict-free (was 8-way on b32)
//  - paired reduce: ALL 256 threads work; lane pair (2m,2m+1) sums row/col
//    partials for y[m] (branchless base select, COLOFF%32=16 -> 2-way = free),
//    one shfl_xor to combine; halves the serial reduce chain
//  - ec2 loads as 2x b128
// All float ops and summation orders are bitwise-identical to round 0.
// (R3 bench was an infra failure — container died twice, no counters; this is
// the same kernel resubmitted after a correctness re-audit.)
__global__ __launch_bounds__(256, 1)
void gfusedmax_kernel(const float* __restrict__ x,
                      const float* __restrict__ A,
                      float* __restrict__ out)
{
    const int b   = blockIdx.x;
    const int tid = threadIdx.x;
    const int tr  = tid >> 4;   // 0..15
    const int tc  = tid & 15;   // 0..15
    const int i0  = tr * 8;
    const int j0  = tc * 8;

    __shared__ __align__(16) float parts[COLOFF + 16 * PST];  // rowpart @0, colpart @COLOFF
    __shared__ __align__(16) float yv[N];
    __shared__ float sorted[N];
    __shared__ float red[8];

    const float step = 1.0f / 256.0f;   // 1/(2N), exact power of two

    // ---- load w = lam*A (lam=1) tile as pairs, init z=0 ----
    v2f w2[8][4];
    v2f z2[8][4];
    const float* Ab = A + (size_t)b * N * N;
    #pragma unroll
    for (int r = 0; r < 8; ++r) {
        const v4f* src = (const v4f*)(Ab + (size_t)(i0 + r) * N + j0);
        v4f p0 = src[0];
        v4f p1 = src[1];
        w2[r][0] = p0.lo; w2[r][1] = p0.hi;
        w2[r][2] = p1.lo; w2[r][3] = p1.hi;
        #pragma unroll
        for (int cp = 0; cp < 4; ++cp) z2[r][cp] = (v2f)0.0f;
    }

    // x value for the y this thread's PAIR computes (m = tid>>1)
    const int m = tid >> 1;
    const float xm = x[(size_t)b * N + m];
    // per-lane partial base: even lanes sum rowparts, odd lanes colparts
    const float* pb = parts + ((tid & 1) ? COLOFF : 0);

    v2f pr2[8], pc2[4];
    #pragma unroll
    for (int r = 0; r < 8; ++r) pr2[r] = (v2f)0.0f;
    #pragma unroll
    for (int cp = 0; cp < 4; ++cp) pc2[cp] = (v2f)0.0f;

    for (int it = 0; it <= NITER; ++it) {
        // (a) publish partials as b128 (conflict-free window distribution)
        v4f r0, r1, c0, c1;
        r0.x = pr2[0].x + pr2[0].y;  r0.y = pr2[1].x + pr2[1].y;
        r0.z = pr2[2].x + pr2[2].y;  r0.w = pr2[3].x + pr2[3].y;
        r1.x = pr2[4].x + pr2[4].y;  r1.y = pr2[5].x + pr2[5].y;
        r1.z = pr2[6].x + pr2[6].y;  r1.w = pr2[7].x + pr2[7].y;
        c0.x = pc2[0].x; c0.y = pc2[0].y; c0.z = pc2[1].x; c0.w = pc2[1].y;
        c1.x = pc2[2].x; c1.y = pc2[2].y; c1.z = pc2[3].x; c1.w = pc2[3].y;
        *(v4f*)&parts[tc * PST + i0]              = r0;
        *(v4f*)&parts[tc * PST + i0 + 4]          = r1;
        *(v4f*)&parts[COLOFF + tr * PST + j0]     = c0;
        *(v4f*)&parts[COLOFF + tr * PST + j0 + 4] = c1;
        __syncthreads();

        // (b) paired reduce: even lane = rowsum(y[m]), odd lane = colsum(y[m]).
        // Sequential k order matches round 0 bitwise. Banks: even (4k+m)%32,
        // odd (4k+m+16)%32 -> uniform 2-way (free).
        float acc = 0.0f;
        #pragma unroll
        for (int k = 0; k < 16; ++k) acc += pb[k * PST + m];
        float other = __shfl_xor(acc, 1, 64);
        if (!(tid & 1)) {
            float y = (xm - acc) + other;   // (x - rs) + cs, same order as round 0
            // scaling by 2^-8 is exact, so step*yi - step*yj == step*(yi-yj)
            yv[m] = (it == NITER) ? y : step * y;
        }
        __syncthreads();
        if (it == NITER) break;

        // (c) packed dual update + partial-sum accumulation
        v2f drs[8], ec2[4];
        #pragma unroll
        for (int r = 0; r < 8; ++r) drs[r] = (v2f)yv[i0 + r];   // 16-lane broadcast
        v4f e0 = *(const v4f*)&yv[j0];
        v4f e1 = *(const v4f*)&yv[j0 + 4];
        ec2[0] = e0.lo; ec2[1] = e0.hi;
        ec2[2] = e1.lo; ec2[3] = e1.hi;
        #pragma unroll
        for (int r = 0; r < 8; ++r) {
            #pragma unroll
            for (int cp = 0; cp < 4; ++cp) {
                v2f t  = (z2[r][cp] + drs[r]) - ec2[cp];   // 2x v_pk_add_f32
                v2f wv = w2[r][cp];
                v2f zn;
                zn.x = __builtin_amdgcn_fmed3f(t.x, -wv.x, wv.x);
                zn.y = __builtin_amdgcn_fmed3f(t.y, -wv.y, wv.y);
                z2[r][cp] = zn;
                pr2[r]  = (cp == 0) ? zn : pr2[r] + zn;    // assign-on-first: saves
                pc2[cp] = (r == 0)  ? zn : pc2[cp] + zn;   // 12 zero-movs per iter
            }
        }
    }

    // ---- sparsemax over yv[0..127] (raw y) ----
    float v = 0.0f;
    if (tid < N) {
        v = yv[tid];
        int rk = 0;
        for (int k = 0; k < N; ++k) {
            float u = yv[k];
            rk += (u > v) || (u == v && k < tid);
        }
        sorted[rk] = v;   // rank is a permutation (ties broken by index)
    }
    __syncthreads();

    float s = 0.0f, csum = 0.0f;
    if (tid < N) {
        s = sorted[tid];
        for (int mm = 0; mm < N; ++mm) {         // uniform index -> LDS broadcast
            float t = sorted[mm];
            if (mm <= tid) csum += t;            // inclusive prefix at sorted pos
        }
    }
    bool mask = (tid < N) && (1.0f + (float)(tid + 1) * s > csum);
    float aRed = mask ? s : 0.0f;
    float bRed = mask ? 1.0f : 0.0f;
    #pragma unroll
    for (int off = 32; off >= 1; off >>= 1) {
        aRed += __shfl_down(aRed, off, 64);
        bRed += __shfl_down(bRed, off, 64);
    }
    const int wid = tid >> 6;
    if ((tid & 63) == 0) { red[wid * 2] = aRed; red[wid * 2 + 1] = bRed; }
    __syncthreads();
    const float tau = (red[0] + red[2] + red[4] + red[6] - 1.0f)
                    / (red[1] + red[3] + red[5] + red[7]);
    if (tid < N) out[(size_t)b * N + tid] = fmaxf(v - tau, 0.0f);
}

extern "C" void kernel_launch(void* const* d_in, const int* in_sizes, int n_in,
                              void* d_out, int out_size, void* d_ws, size_t ws_size,
                              hipStream_t stream) {
    const float* x = (const float*)d_in[0];
    const float* A = (const float*)d_in[1];
    float* out = (float*)d_out;
    const int B = in_sizes[0] / N;   // 4096 rows
    gfusedmax_kernel<<<B, 256, 0, stream>>>(x, A, out);
}